// Round 2
// baseline (34349.203 us; speedup 1.0000x reference)
//
#include <hip/hip_runtime.h>

#define T_DIM 512
#define B_DIM 256
#define S_DIMS 64
#define A_DIMS 16
#define E_DIM 128
#define H_DIM 512
#define X_DIM 384   // 3*E
#define G_DIM 1536  // 3*H

__device__ __forceinline__ float gelu_tanh(float x) {
    const float c = 0.7978845608028654f; // sqrt(2/pi)
    float x3 = x * x * x;
    return 0.5f * x * (1.0f + tanhf(c * (x + 0.044715f * x3)));
}

__device__ __forceinline__ float sigmoidf(float x) {
    return 1.0f / (1.0f + expf(-x));
}

// ---------------- Embedding kernel: x = [gelu(s@Ws+bs), gelu(a@Wa+ba), gelu(r@Wr+br)]
__global__ __launch_bounds__(256) void embed_kernel(
    const float* __restrict__ s, const float* __restrict__ a, const float* __restrict__ r,
    const float* __restrict__ Ws, const float* __restrict__ bs,
    const float* __restrict__ Wa, const float* __restrict__ ba,
    const float* __restrict__ Wr, const float* __restrict__ br,
    float* __restrict__ x)
{
    __shared__ float Ws_s[64][128];
    __shared__ float Wa_s[16][128];
    __shared__ float Wr_s[128], bs_s[128], ba_s[128], br_s[128];
    __shared__ float s_s[64][64];
    __shared__ float a_s[64][16];
    __shared__ float r_s[64];
    int tid = threadIdx.x;
    for (int i = tid; i < 64 * 128; i += 256) Ws_s[i >> 7][i & 127] = Ws[i];
    for (int i = tid; i < 16 * 128; i += 256) Wa_s[i >> 7][i & 127] = Wa[i];
    if (tid < 128) { Wr_s[tid] = Wr[tid]; bs_s[tid] = bs[tid]; ba_s[tid] = ba[tid]; br_s[tid] = br[tid]; }
    size_t row0 = (size_t)blockIdx.x * 64;
    for (int i = tid; i < 64 * 64; i += 256) s_s[i >> 6][i & 63] = s[row0 * 64 + i];
    for (int i = tid; i < 64 * 16; i += 256) a_s[i >> 4][i & 15] = a[row0 * 16 + i];
    if (tid < 64) r_s[tid] = r[row0 + tid];
    __syncthreads();
    int e = tid & 127, ty = tid >> 7;
    for (int rw = ty; rw < 64; rw += 2) {
        float accS = bs_s[e];
        #pragma unroll
        for (int k = 0; k < 64; ++k) accS += s_s[rw][k] * Ws_s[k][e];
        float accA = ba_s[e];
        #pragma unroll
        for (int k = 0; k < 16; ++k) accA += a_s[rw][k] * Wa_s[k][e];
        float accR = br_s[e] + r_s[rw] * Wr_s[e];
        size_t base = (row0 + rw) * X_DIM;
        x[base + e]       = gelu_tanh(accS);
        x[base + 128 + e] = gelu_tanh(accA);
        x[base + 256 + e] = gelu_tanh(accR);
    }
}

// ---------------- Gates GEMM: C[m][n] = sum_k A[m][k]*B[k][n] + bias[n]
__global__ __launch_bounds__(256) void gates_gemm(
    const float* __restrict__ A, const float* __restrict__ B,
    const float* __restrict__ bias, float* __restrict__ C)
{
    __shared__ float As[32][132];
    __shared__ float Bs[32][132];
    const int K = X_DIM;
    int tid = threadIdx.x;
    size_t m0 = (size_t)blockIdx.x * 128;
    int n0 = blockIdx.y * 128;
    int tx = tid & 15, ty = tid >> 4;
    float acc[8][8] = {};
    for (int k0 = 0; k0 < K; k0 += 32) {
        #pragma unroll
        for (int p = 0; p < 4; ++p) {
            int row = (tid >> 3) + p * 32;
            int k4 = (tid & 7) * 4;
            float4 v = *reinterpret_cast<const float4*>(&A[(m0 + row) * K + k0 + k4]);
            As[k4 + 0][row] = v.x; As[k4 + 1][row] = v.y;
            As[k4 + 2][row] = v.z; As[k4 + 3][row] = v.w;
        }
        {
            int k = tid >> 3;
            int cb = (tid & 7) * 16;
            #pragma unroll
            for (int q = 0; q < 4; ++q) {
                float4 v = *reinterpret_cast<const float4*>(&B[(size_t)(k0 + k) * G_DIM + n0 + cb + q * 4]);
                *reinterpret_cast<float4*>(&Bs[k][cb + q * 4]) = v;
            }
        }
        __syncthreads();
        #pragma unroll
        for (int k = 0; k < 32; ++k) {
            float4 a0 = *reinterpret_cast<const float4*>(&As[k][ty * 8]);
            float4 a1 = *reinterpret_cast<const float4*>(&As[k][ty * 8 + 4]);
            float4 b0 = *reinterpret_cast<const float4*>(&Bs[k][tx * 8]);
            float4 b1 = *reinterpret_cast<const float4*>(&Bs[k][tx * 8 + 4]);
            float av[8] = {a0.x, a0.y, a0.z, a0.w, a1.x, a1.y, a1.z, a1.w};
            float bv[8] = {b0.x, b0.y, b0.z, b0.w, b1.x, b1.y, b1.z, b1.w};
            #pragma unroll
            for (int i = 0; i < 8; ++i)
                #pragma unroll
                for (int j = 0; j < 8; ++j)
                    acc[i][j] += av[i] * bv[j];
        }
        __syncthreads();
    }
    #pragma unroll
    for (int i = 0; i < 8; ++i) {
        size_t crow = (m0 + ty * 8 + i) * G_DIM + n0 + tx * 8;
        float4 o0, o1;
        o0.x = acc[i][0] + bias[n0 + tx * 8 + 0];
        o0.y = acc[i][1] + bias[n0 + tx * 8 + 1];
        o0.z = acc[i][2] + bias[n0 + tx * 8 + 2];
        o0.w = acc[i][3] + bias[n0 + tx * 8 + 3];
        o1.x = acc[i][4] + bias[n0 + tx * 8 + 4];
        o1.y = acc[i][5] + bias[n0 + tx * 8 + 5];
        o1.z = acc[i][6] + bias[n0 + tx * 8 + 6];
        o1.w = acc[i][7] + bias[n0 + tx * 8 + 7];
        *reinterpret_cast<float4*>(&C[crow]) = o0;
        *reinterpret_cast<float4*>(&C[crow + 4]) = o1;
    }
}

// ---------------- GRU step part 1: zr = sigmoid(gx_zr + h @ w_h[:, :1024])
// writes z (B x 512) and rh = r * h_prev (B x 512).
// grid (N/64=16, M/64=4), 256 threads, 64x64 tile, 4x4 micro.
__global__ __launch_bounds__(256) void gru_zr(
    const float* __restrict__ gxb,   // B x 1536
    const float* __restrict__ hprev, // B x 512 or nullptr
    const float* __restrict__ w_h,   // 512 x 1536
    float* __restrict__ zbuf,        // B x 512
    float* __restrict__ rhbuf)       // B x 512
{
    __shared__ float As[32][68];
    __shared__ float Bs[32][68];
    int tid = threadIdx.x;
    int n0 = blockIdx.x * 64;
    int m0 = blockIdx.y * 64;
    int tx = tid & 15, ty = tid >> 4;
    float acc[4][4] = {};
    if (hprev) {
        for (int k0 = 0; k0 < H_DIM; k0 += 32) {
            #pragma unroll
            for (int p = 0; p < 2; ++p) {
                int row = (tid >> 3) + p * 32;
                int k4 = (tid & 7) * 4;
                float4 v = *reinterpret_cast<const float4*>(&hprev[(size_t)(m0 + row) * H_DIM + k0 + k4]);
                As[k4 + 0][row] = v.x; As[k4 + 1][row] = v.y;
                As[k4 + 2][row] = v.z; As[k4 + 3][row] = v.w;
            }
            {
                int k = tid >> 3;
                int c = (tid & 7) * 8;
                float4 v0 = *reinterpret_cast<const float4*>(&w_h[(size_t)(k0 + k) * G_DIM + n0 + c]);
                float4 v1 = *reinterpret_cast<const float4*>(&w_h[(size_t)(k0 + k) * G_DIM + n0 + c + 4]);
                *reinterpret_cast<float4*>(&Bs[k][c])     = v0;
                *reinterpret_cast<float4*>(&Bs[k][c + 4]) = v1;
            }
            __syncthreads();
            #pragma unroll
            for (int k = 0; k < 32; ++k) {
                float4 a4 = *reinterpret_cast<const float4*>(&As[k][ty * 4]);
                float4 b4 = *reinterpret_cast<const float4*>(&Bs[k][tx * 4]);
                float av[4] = {a4.x, a4.y, a4.z, a4.w};
                float bv[4] = {b4.x, b4.y, b4.z, b4.w};
                #pragma unroll
                for (int i = 0; i < 4; ++i)
                    #pragma unroll
                    for (int j = 0; j < 4; ++j)
                        acc[i][j] += av[i] * bv[j];
            }
            __syncthreads();
        }
    }
    #pragma unroll
    for (int i = 0; i < 4; ++i) {
        int row = m0 + ty * 4 + i;
        #pragma unroll
        for (int j = 0; j < 4; ++j) {
            int col = n0 + tx * 4 + j;
            float val = sigmoidf(gxb[(size_t)row * G_DIM + col] + acc[i][j]);
            if (col < H_DIM) {
                zbuf[(size_t)row * H_DIM + col] = val;
            } else {
                int c = col - H_DIM;
                float hp = hprev ? hprev[(size_t)row * H_DIM + c] : 0.0f;
                rhbuf[(size_t)row * H_DIM + c] = val * hp;
            }
        }
    }
}

// ---------------- GRU step part 2: a = tanh(gx_a + rh @ w_h[:, 1024:]); h = hp + z*(a-hp)
// grid (N/64=8, M/64=4), 256 threads.
__global__ __launch_bounds__(256) void gru_a(
    const float* __restrict__ gxb,   // B x 1536
    const float* __restrict__ hprev, // B x 512 or nullptr (t==0; rhbuf invalid then)
    const float* __restrict__ rhbuf, // B x 512
    const float* __restrict__ zbuf,  // B x 512
    const float* __restrict__ w_h,   // 512 x 1536
    float* __restrict__ hout)        // B x 512
{
    __shared__ float As[32][68];
    __shared__ float Bs[32][68];
    int tid = threadIdx.x;
    int n0 = blockIdx.x * 64;
    int m0 = blockIdx.y * 64;
    int tx = tid & 15, ty = tid >> 4;
    float acc[4][4] = {};
    if (hprev) {
        for (int k0 = 0; k0 < H_DIM; k0 += 32) {
            #pragma unroll
            for (int p = 0; p < 2; ++p) {
                int row = (tid >> 3) + p * 32;
                int k4 = (tid & 7) * 4;
                float4 v = *reinterpret_cast<const float4*>(&rhbuf[(size_t)(m0 + row) * H_DIM + k0 + k4]);
                As[k4 + 0][row] = v.x; As[k4 + 1][row] = v.y;
                As[k4 + 2][row] = v.z; As[k4 + 3][row] = v.w;
            }
            {
                int k = tid >> 3;
                int c = (tid & 7) * 8;
                float4 v0 = *reinterpret_cast<const float4*>(&w_h[(size_t)(k0 + k) * G_DIM + 2 * H_DIM + n0 + c]);
                float4 v1 = *reinterpret_cast<const float4*>(&w_h[(size_t)(k0 + k) * G_DIM + 2 * H_DIM + n0 + c + 4]);
                *reinterpret_cast<float4*>(&Bs[k][c])     = v0;
                *reinterpret_cast<float4*>(&Bs[k][c + 4]) = v1;
            }
            __syncthreads();
            #pragma unroll
            for (int k = 0; k < 32; ++k) {
                float4 a4 = *reinterpret_cast<const float4*>(&As[k][ty * 4]);
                float4 b4 = *reinterpret_cast<const float4*>(&Bs[k][tx * 4]);
                float av[4] = {a4.x, a4.y, a4.z, a4.w};
                float bv[4] = {b4.x, b4.y, b4.z, b4.w};
                #pragma unroll
                for (int i = 0; i < 4; ++i)
                    #pragma unroll
                    for (int j = 0; j < 4; ++j)
                        acc[i][j] += av[i] * bv[j];
            }
            __syncthreads();
        }
    }
    #pragma unroll
    for (int i = 0; i < 4; ++i) {
        int row = m0 + ty * 4 + i;
        #pragma unroll
        for (int j = 0; j < 4; ++j) {
            int col = n0 + tx * 4 + j;
            float av = tanhf(gxb[(size_t)row * G_DIM + 2 * H_DIM + col] + acc[i][j]);
            float hp = hprev ? hprev[(size_t)row * H_DIM + col] : 0.0f;
            float z = zbuf[(size_t)row * H_DIM + col];
            hout[(size_t)row * H_DIM + col] = hp + z * (av - hp);
        }
    }
}

extern "C" void kernel_launch(void* const* d_in, const int* in_sizes, int n_in,
                              void* d_out, int out_size, void* d_ws, size_t ws_size,
                              hipStream_t stream) {
    const float* states  = (const float*)d_in[0];
    const float* actions = (const float*)d_in[1];
    const float* rewards = (const float*)d_in[2];
    const float* Ws   = (const float*)d_in[3];
    const float* bs   = (const float*)d_in[4];
    const float* Wa   = (const float*)d_in[5];
    const float* ba   = (const float*)d_in[6];
    const float* Wr   = (const float*)d_in[7];
    const float* br   = (const float*)d_in[8];
    const float* w_i  = (const float*)d_in[9];
    const float* w_h  = (const float*)d_in[10];
    const float* bgru = (const float*)d_in[11];
    float* out = (float*)d_out;

    // ws layout: [zbuf: B*512][rhbuf: B*512][gx: chunk*B*1536][xbuf: chunk*B*384]
    size_t fixed = (size_t)2 * B_DIM * H_DIM * sizeof(float); // 1 MiB
    size_t per_step = (size_t)B_DIM * (G_DIM + X_DIM) * sizeof(float); // ~1.97 MB
    int chunk = (int)((ws_size > fixed ? ws_size - fixed : 0) / per_step);
    if (chunk > T_DIM) chunk = T_DIM;
    if (chunk < 1) chunk = 1;
    float* zbuf  = (float*)d_ws;
    float* rhbuf = zbuf + (size_t)B_DIM * H_DIM;
    float* gx    = rhbuf + (size_t)B_DIM * H_DIM;
    float* xbuf  = gx + (size_t)chunk * B_DIM * G_DIM;

    for (int t0 = 0; t0 < T_DIM; t0 += chunk) {
        int nt = (T_DIM - t0 < chunk) ? (T_DIM - t0) : chunk;
        int rows = nt * B_DIM;
        embed_kernel<<<rows / 64, 256, 0, stream>>>(
            states + (size_t)t0 * B_DIM * S_DIMS,
            actions + (size_t)t0 * B_DIM * A_DIMS,
            rewards + (size_t)t0 * B_DIM,
            Ws, bs, Wa, ba, Wr, br, xbuf);
        dim3 ggrid(rows / 128, G_DIM / 128);
        gates_gemm<<<ggrid, 256, 0, stream>>>(xbuf, w_i, bgru, gx);
        for (int s = 0; s < nt; ++s) {
            int t = t0 + s;
            const float* hprev = (t == 0) ? nullptr : out + (size_t)(t - 1) * B_DIM * H_DIM;
            const float* gxb = gx + (size_t)s * B_DIM * G_DIM;
            dim3 zgrid(2 * H_DIM / 64, B_DIM / 64);
            gru_zr<<<zgrid, 256, 0, stream>>>(gxb, hprev, w_h, zbuf, rhbuf);
            dim3 agrid(H_DIM / 64, B_DIM / 64);
            gru_a<<<agrid, 256, 0, stream>>>(gxb, hprev, rhbuf, zbuf, w_h,
                                             out + (size_t)t * B_DIM * H_DIM);
        }
    }
}